// Round 9
// baseline (1425.957 us; speedup 1.0000x reference)
//
#include <hip/hip_runtime.h>
#include <cmath>

#define HID 51
#define BATCH 256
#define BLK 1024     // 16 waves
#define NR 204       // 4*HID gate rows per matrix

typedef _Float16 half2_t __attribute__((ext_vector_type(2)));

// One block per batch element (grid = 256 = #CUs). R1's proven 2-phase /
// 2-barrier schedule (gates->cell same tick across bar1; cell->next dots
// across bar2) -- shown irreducible for cross-wave cells -- with every
// measured inefficiency of R1 removed:
//  - BALANCED role map: global row R = tid indexes the concatenation
//    [L0 gates | L1 Wih | L1 Whh | L2 Wih | L2 Whh | out] (1021 rows over
//    1024 lanes, 26 dots per lane, uniform code path). No straggler wave
//    (R1's wave 15 ran a separate per-lane float4 path -> late barrier).
//  - h broadcast via 7 uniform-address int4 LDS loads unpacked to SCALAR
//    ints (R6-validated, SROA-safe): no v_readlane (~208 cy/SIMD in R1).
//  - gP keeps R1's conflict-cheap scalar [role][g] layout (R7's quad
//    layout was a 48M-conflict regression).
//  - cells layer-aligned: wave l = layer l (SIMD l), lanes 0..50; flush on
//    wave 3 (SIMD 3). Cell waves carry role-0 dots (shortest role) so they
//    reach bar1 early; s_setprio(1) on them (T5: role diversity exists).
// Roles (t = tau - lp): 0: L0 bias+wx*x[t]+Whh1.h0 (lp0)  1: L1 Wih.h0
// (lp1, bias)  2: L1 Whh.h1 (lp1)  3: L2 Wih.h1 (lp2, bias)  4: L2 Whh.h2
// (lp2)  5: out Wl.h2+bl -> obuf (lp3). Cell l at tick tau: t = tau - l.
// Flush: block [F,F+64) at tau = F+66 (out(F+63) written phase A same
// tick; bar1 orders it). TICKS = T+3.

__device__ __forceinline__ float fsig(float v) {
    return __builtin_amdgcn_rcpf(1.f + __expf(-v));
}
__device__ __forceinline__ float ftanh(float v) {
    const float e = __expf(2.f * v);                 // inf-safe
    return fmaf(-2.f, __builtin_amdgcn_rcpf(e + 1.f), 1.f);
}
__device__ __forceinline__ half2_t h2bits(int b) {
    union { int i; half2_t h; } u; u.i = b; return u.h;
}

__attribute__((amdgpu_waves_per_eu(4, 4)))
__global__ __launch_bounds__(BLK)
void lstm3_kernel(const float* __restrict__ x,
                  const float* __restrict__ Wih1, const float* __restrict__ Whh1,
                  const float* __restrict__ bih1, const float* __restrict__ bhh1,
                  const float* __restrict__ Wih,  const float* __restrict__ Whh,
                  const float* __restrict__ bih,  const float* __restrict__ bhh,
                  const float* __restrict__ Wl,   const float* __restrict__ bl,
                  float* __restrict__ out, int T)
{
    const int b    = blockIdx.x;
    const int tid  = threadIdx.x;
    const int wave = tid >> 6;
    const int lane = tid & 63;

    __shared__ __align__(16) float xbuf[2048];
    __shared__ __align__(16) int   hrow[3][32];      // h fp16 pairs, 128B rows
    __shared__ __align__(16) float gP[5][NR];        // gate partials [gate*51+u]
    __shared__ __align__(16) float obuf[128];        // output ring (2 x 64)

    for (int i = tid; i < T; i += BLK) xbuf[i] = x[(size_t)b * T + i];
    if (tid < 96) ((int*)hrow)[tid] = 0;             // h = 0 incl. pads

    // ---------------- balanced phase-A role map: row R = tid ----------------
    int role, g = 0;
    if      (tid < 204)  { role = 0; g = tid; }
    else if (tid < 408)  { role = 1; g = tid - 204; }
    else if (tid < 612)  { role = 2; g = tid - 408; }
    else if (tid < 816)  { role = 3; g = tid - 612; }
    else if (tid < 1020) { role = 4; g = tid - 816; }
    else if (tid == 1020){ role = 5; }
    else                 { role = -1; }

    const float* rowp = nullptr;
    float wx = 0.f, bias = 0.f;
    int srcrow = 0, lp = 1 << 20;
    if (role == 0) {
        wx   = Wih1[g];
        bias = bih1[g] + bhh1[g];
        rowp = Whh1 + (size_t)g * HID;
        srcrow = 0; lp = 0;
    } else if (role == 1) {
        bias = bih[g] + bhh[g];
        rowp = Wih + (size_t)g * HID;
        srcrow = 0; lp = 1;
    } else if (role == 2) {
        rowp = Whh + (size_t)g * HID;
        srcrow = 1; lp = 1;
    } else if (role == 3) {
        bias = bih[NR + g] + bhh[NR + g];
        rowp = Wih + (size_t)(NR + g) * HID;
        srcrow = 1; lp = 2;
    } else if (role == 4) {
        rowp = Whh + (size_t)(NR + g) * HID;
        srcrow = 2; lp = 2;
    } else if (role == 5) {
        bias = bl[0];
        rowp = Wl;
        srcrow = 2; lp = 3;
    }
    float* dst = (role >= 0 && role < 5) ? &gP[role][g] : nullptr;
    const int4* hp = (const int4*)((const char*)hrow + srcrow * 128);

    half2_t w2[26];
    #pragma unroll
    for (int j = 0; j < 26; ++j) w2[j] = half2_t{(_Float16)0.f, (_Float16)0.f};
    if (rowp) {
        #pragma unroll
        for (int j = 0; j < 25; ++j)
            w2[j] = half2_t{(_Float16)rowp[2*j], (_Float16)rowp[2*j+1]};
        w2[25] = half2_t{(_Float16)rowp[50], (_Float16)0.f};
    }

    // ---------------- phase-B role (layer-aligned cell waves) ----------------
    const bool is_cell = (wave < 3) && (lane < HID);
    float c_state = 0.f;
    if (wave < 3) __builtin_amdgcn_s_setprio(1);     // cell waves: critical path

    __syncthreads();

    const int TICKS = T + 3;
    for (int tau = 0; tau < TICKS; ++tau) {
        // ---------------- phase A: one 26-pair dot row per lane ----------------
        if (role >= 0) {
            const int  t    = tau - lp;              // per-lane (role-dependent)
            const bool pred = (unsigned)t < (unsigned)T;
            int hw[28];                              // scalar unpack: SROA-safe
            #pragma unroll
            for (int k = 0; k < 7; ++k) {
                const int4 q = hp[k];                // broadcast (<=2 addrs/wave)
                hw[4*k+0] = q.x; hw[4*k+1] = q.y; hw[4*k+2] = q.z; hw[4*k+3] = q.w;
            }
            float acc0 = fmaf(wx, xbuf[pred ? t : 0], bias);  // wx=0 unless role 0
            float acc1 = 0.f;
            #pragma unroll
            for (int j = 0; j < 26; ++j) {
                const half2_t hj = h2bits(hw[j]);
                if (j & 1) acc1 = __builtin_amdgcn_fdot2(w2[j], hj, acc1, false);
                else       acc0 = __builtin_amdgcn_fdot2(w2[j], hj, acc0, false);
            }
            if (pred) {
                if (dst) *dst = acc0 + acc1;
                else     obuf[t & 127] = acc0 + acc1;          // out lane
            }
        }
        __syncthreads();                             // bar1: gates -> cells
        // ---------------- phase B: cells (1 wave/SIMD) + flush ----------------
        if (is_cell) {
            const int t = tau - wave;                // wave-uniform
            if ((unsigned)t < (unsigned)T) {
                const float* pW = gP[wave == 0 ? 0 : (wave == 1 ? 2 : 4)];
                float gi  = pW[lane];
                float gf  = pW[HID + lane];
                float gg_ = pW[2 * HID + lane];
                float go  = pW[3 * HID + lane];
                if (wave > 0) {                      // add Wih partials (w/ bias)
                    const float* pI = gP[wave == 1 ? 1 : 3];
                    gi  += pI[lane];
                    gf  += pI[HID + lane];
                    gg_ += pI[2 * HID + lane];
                    go  += pI[3 * HID + lane];
                }
                const float c = fmaf(fsig(gf), c_state, fsig(gi) * ftanh(gg_));
                c_state = c;
                ((_Float16*)&hrow[wave][0])[lane] = (_Float16)(fsig(go) * ftanh(c));
            }
        } else if (wave == 3 && (tau & 63) == 2 && tau >= 66) {
            // out(F+63) written in THIS tick's phase A; bar1 ordered it
            const int t0 = tau - 66;                 // multiple of 64
            out[(size_t)b * T + t0 + lane] = obuf[(t0 & 64) + lane];
        }
        __syncthreads();                             // bar2: h -> next dots
    }
}

extern "C" void kernel_launch(void* const* d_in, const int* in_sizes, int n_in,
                              void* d_out, int out_size, void* d_ws, size_t ws_size,
                              hipStream_t stream) {
    const float* x    = (const float*)d_in[0];
    const float* Wih1 = (const float*)d_in[1];
    const float* Whh1 = (const float*)d_in[2];
    const float* bih1 = (const float*)d_in[3];
    const float* bhh1 = (const float*)d_in[4];
    const float* Wih  = (const float*)d_in[5];
    const float* Whh  = (const float*)d_in[6];
    const float* bih  = (const float*)d_in[7];
    const float* bhh  = (const float*)d_in[8];
    const float* Wl   = (const float*)d_in[9];
    const float* bl   = (const float*)d_in[10];
    float* out = (float*)d_out;

    const int T = in_sizes[0] / BATCH;   // 2048 (flush assumes T % 64 == 0)
    lstm3_kernel<<<BATCH, BLK, 0, stream>>>(x, Wih1, Whh1, bih1, bhh1,
                                            Wih, Whh, bih, bhh, Wl, bl, out, T);
}